// Round 4
// baseline (103.543 us; speedup 1.0000x reference)
//
#include <hip/hip_runtime.h>
#include <hip/hip_bf16.h>
#include <math.h>

// FuzzyAND: out[b,j] = max(0, 1 - sum_i sigmoid(W)[i,j] * (1 - xs[b,i]))
// B=4096, IN=1024, OUT=1024, fp32 in/out.
// R4: LDS-free, barrier-free GEMM. prep packs A=bf16(1-xs) and
// B=bf16(sigmoid(W))^T into MFMA-fragment-chunk-major layout (1KB per
// 16x16x32 fragment: byte = chunk*1024 + lane*16 + j*2). GEMM loads frags
// directly global->VGPR (1KB coalesced per instruction), 4-deep chunk
// pipeline hides L2 latency, per-wave 64x64 (4x4 frags) so frag traffic
// is 0.5KB/MFMA (~160MB total, L2-resident via XCD-clustered decode).

constexpr int Bsz = 4096;
constexpr int IN  = 1024;
constexpr int OUT = 1024;
constexpr int KCH = IN / 32;   // 32 k-chunks of K=32

typedef __attribute__((ext_vector_type(8))) short bf16x8;  // 8 bf16 = 4 VGPRs
typedef __attribute__((ext_vector_type(4))) float f32x4;

__device__ inline unsigned short f2bf(float f) {
    union { float f; unsigned u; } c{f};
    unsigned lsb = (c.u >> 16) & 1u;
    unsigned r = c.u + 0x7fffu + lsb;   // round-to-nearest-even
    return (unsigned short)(r >> 16);
}

// ---- fused prep ----
// blocks [0,2048): pack A. gid = chunk*64 + lane; chunk = mtile*KCH + kch.
//   element: m = mtile*16 + (lane&15), k = kch*32 + (lane>>4)*8 + j.
//   write addr = Apk + gid*8 ushorts  (perfectly linear).
// blocks [2048,3072): sigmoid + transpose + pack W -> Bpk (same chunk layout,
//   n in place of m, via 32x32 LDS tile).
__global__ void prep_fused(const float* __restrict__ xs, const float* __restrict__ w,
                           unsigned short* __restrict__ Apk, unsigned short* __restrict__ Bpk) {
    if (blockIdx.x < 2048) {
        int gid = blockIdx.x * 256 + threadIdx.x;          // [0, 512K)
        int m  = ((gid >> 11) << 4) | (gid & 15);          // mtile*16 + l16
        int k0 = (((gid >> 6) & 31) << 5) | (((gid >> 4) & 3) << 3);  // kch*32 + quad*8
        const float4* p = (const float4*)(xs + (size_t)m * IN + k0);
        float4 a = p[0], b = p[1];
        bf16x8 o;
        o[0] = (short)f2bf(1.0f - a.x); o[1] = (short)f2bf(1.0f - a.y);
        o[2] = (short)f2bf(1.0f - a.z); o[3] = (short)f2bf(1.0f - a.w);
        o[4] = (short)f2bf(1.0f - b.x); o[5] = (short)f2bf(1.0f - b.y);
        o[6] = (short)f2bf(1.0f - b.z); o[7] = (short)f2bf(1.0f - b.w);
        *(bf16x8*)(Apk + (size_t)gid * 8) = o;
    } else {
        __shared__ unsigned short t[32][33];
        int wb = blockIdx.x - 2048;
        int o0 = (wb & 31) * 32, i0 = (wb >> 5) * 32;
        int tx = threadIdx.x & 31, ty = threadIdx.x >> 5;
#pragma unroll
        for (int r = 0; r < 4; ++r) {
            int row = ty + r * 8;  // i-local
            float v = w[(size_t)(i0 + row) * OUT + o0 + tx];
            float s = 1.0f / (1.0f + __expf(-v));
            t[row][tx] = f2bf(s);
        }
        __syncthreads();
        if (threadIdx.x < 128) {
            int cs   = threadIdx.x >> 6;          // which of the 2 o-tiles
            int lane = threadIdx.x & 63;
            int l16  = lane & 15, quad = lane >> 4;
            int chunk = ((o0 >> 4) + cs) * KCH + (i0 >> 5);
            bf16x8 o;
#pragma unroll
            for (int j = 0; j < 8; ++j)
                o[j] = (short)t[quad * 8 + j][cs * 16 + l16];
            *(bf16x8*)(Bpk + (size_t)chunk * 512 + lane * 8) = o;
        }
    }
}

// ---- GEMM: C[m][n] = max(0, 1 - sum_k A[m][k] * WT[n][k]) ----
// 256 blocks x 4 waves; wave = 64x64 output (4x4 frags). No LDS, no barriers.
// Block decode clusters m-quads per XCD (A footprint 1MB + B 2MB < 4MB L2/XCD).
__global__ __launch_bounds__(256) void gemm_fuzzy(const unsigned short* __restrict__ Apk,
                                                  const unsigned short* __restrict__ Bpk,
                                                  float* __restrict__ C) {
    const int bx     = blockIdx.x;
    const int m_quad = ((bx & 7) << 1) | ((bx >> 3) & 1);  // [0,16)
    const int n_idx  = bx >> 4;                            // [0,16)
    const int wave   = threadIdx.x >> 6;
    const int lane   = threadIdx.x & 63;
    const int l16    = lane & 15;
    const int quad   = lane >> 4;
    const int m_idx  = m_quad * 4 + wave;                  // [0,64) 64-row tile

    // frag(mt, c) at base + (mt*KCH + c)*512 ushorts
    const unsigned short* Ab = Apk + ((size_t)m_idx * 4 * KCH) * 512 + lane * 8;
    const unsigned short* Bb = Bpk + ((size_t)n_idx * 4 * KCH) * 512 + lane * 8;

    bf16x8 rA[4][4], rB[4][4];
    f32x4 acc[4][4] = {};

#pragma unroll
    for (int c = 0; c < 4; ++c)
#pragma unroll
        for (int t = 0; t < 4; ++t) {
            rA[c][t] = *(const bf16x8*)(Ab + ((size_t)t * KCH + c) * 512);
            rB[c][t] = *(const bf16x8*)(Bb + ((size_t)t * KCH + c) * 512);
        }

#define STEP(C_, S_)                                                          \
    {                                                                         \
        _Pragma("unroll") for (int mt = 0; mt < 4; ++mt)                      \
            _Pragma("unroll") for (int nt = 0; nt < 4; ++nt)                  \
                acc[mt][nt] = __builtin_amdgcn_mfma_f32_16x16x32_bf16(        \
                    rA[S_][mt], rB[S_][nt], acc[mt][nt], 0, 0, 0);            \
        if ((C_) + 4 < KCH) {                                                 \
            _Pragma("unroll") for (int t = 0; t < 4; ++t) {                   \
                rA[S_][t] = *(const bf16x8*)(Ab + ((size_t)t * KCH + (C_) + 4) * 512); \
                rB[S_][t] = *(const bf16x8*)(Bb + ((size_t)t * KCH + (C_) + 4) * 512); \
            }                                                                 \
        }                                                                     \
    }

    for (int q = 0; q < KCH; q += 4) {
        STEP(q + 0, 0)
        STEP(q + 1, 1)
        STEP(q + 2, 2)
        STEP(q + 3, 3)
    }
#undef STEP

    // epilogue: C/D layout col=lane&15, row=quad*4+reg; fuse 1-s and clamp
    const int m0 = m_idx * 64, n0 = n_idx * 64;
#pragma unroll
    for (int mt = 0; mt < 4; ++mt) {
#pragma unroll
        for (int nt = 0; nt < 4; ++nt) {
#pragma unroll
            for (int r = 0; r < 4; ++r) {
                int row = m0 + mt * 16 + quad * 4 + r;
                int col = n0 + nt * 16 + l16;
                float v = 1.0f - acc[mt][nt][r];
                C[(size_t)row * OUT + col] = fmaxf(v, 0.0f);
            }
        }
    }
}

extern "C" void kernel_launch(void* const* d_in, const int* in_sizes, int n_in,
                              void* d_out, int out_size, void* d_ws, size_t ws_size,
                              hipStream_t stream) {
    const float* xs = (const float*)d_in[0];       // [4096][1024]
    const float* wt = (const float*)d_in[1];       // [1024][1024]
    float* out = (float*)d_out;                    // [4096][1024]

    unsigned short* Apk = (unsigned short*)d_ws;                                  // 8 MB
    unsigned short* Bpk = (unsigned short*)((char*)d_ws + (size_t)Bsz * IN * 2);  // 2 MB

    prep_fused<<<2048 + 1024, 256, 0, stream>>>(xs, wt, Apk, Bpk);
    gemm_fuzzy<<<256, 256, 0, stream>>>(Apk, Bpk, out);
}

// Round 5
// 87.967 us; speedup vs baseline: 1.1771x; 1.1771x over previous
//
#include <hip/hip_runtime.h>
#include <hip/hip_bf16.h>
#include <math.h>

// FuzzyAND: out[b,j] = max(0, 1 - sum_i sigmoid(W)[i,j] * (1 - xs[b,i]))
// B=4096, IN=1024, OUT=1024, fp32 in/out.
// R5: 128x128x64 tiles, 4 waves of 64x64 (4x4 frags -> ds_read:MFMA = 1:2,
// the best LDS ratio), R3-style reg staging (global->VGPR 2 iters ahead ->
// ds_write -> lgkm-only barrier; no vmcnt(0) drain). 256 blocks = 1/CU,
// XCD-clustered n (bx&7) keeps each XCD's 256KB B-tile L2-hot.

constexpr int Bsz = 4096;
constexpr int IN  = 1024;
constexpr int OUT = 1024;

constexpr int BM = 128;
constexpr int BN = 128;
constexpr int BK = 64;

typedef __attribute__((ext_vector_type(8))) short bf16x8;  // 8 bf16 = 4 VGPRs
typedef __attribute__((ext_vector_type(4))) float f32x4;

__device__ inline unsigned short f2bf(float f) {
    union { float f; unsigned u; } c{f};
    unsigned lsb = (c.u >> 16) & 1u;
    unsigned r = c.u + 0x7fffu + lsb;   // round-to-nearest-even
    return (unsigned short)(r >> 16);
}

// ---- fused prep: blocks [0,2048) -> A = bf16(1-xs); [2048,3072) -> WT = bf16(sigmoid(W))^T
__global__ void prep_fused(const float* __restrict__ xs, const float* __restrict__ w,
                           unsigned short* __restrict__ A, unsigned short* __restrict__ WT) {
    if (blockIdx.x < 2048) {
        int idx = (blockIdx.x * 256 + threadIdx.x) * 2;  // float4 index
        float4 v0 = ((const float4*)xs)[idx];
        float4 v1 = ((const float4*)xs)[idx + 1];
        ushort4 o0, o1;
        o0.x = f2bf(1.0f - v0.x); o0.y = f2bf(1.0f - v0.y);
        o0.z = f2bf(1.0f - v0.z); o0.w = f2bf(1.0f - v0.w);
        o1.x = f2bf(1.0f - v1.x); o1.y = f2bf(1.0f - v1.y);
        o1.z = f2bf(1.0f - v1.z); o1.w = f2bf(1.0f - v1.w);
        ((ushort4*)A)[idx]     = o0;
        ((ushort4*)A)[idx + 1] = o1;
    } else {
        __shared__ unsigned short t[32][33];
        int wblk = blockIdx.x - 2048;
        int o0 = (wblk & 31) * 32, i0 = (wblk >> 5) * 32;
        int tx = threadIdx.x & 31, ty = threadIdx.x >> 5;
#pragma unroll
        for (int r = 0; r < 4; ++r) {
            int row = ty + r * 8;  // i-local
            float v = w[(size_t)(i0 + row) * OUT + o0 + tx];
            float s = 1.0f / (1.0f + __expf(-v));
            t[row][tx] = f2bf(s);
        }
        __syncthreads();
#pragma unroll
        for (int r = 0; r < 4; ++r) {
            int row = ty + r * 8;  // o-local
            WT[(size_t)(o0 + row) * IN + i0 + tx] = t[tx][row];
        }
    }
}

// ---- GEMM: C[m][n] = max(0, 1 - sum_k A[m][k] * WT[n][k]) ----
// LDS layout per tile: row r (64 bf16 = 8 chunks of 8), chunk kc at slot
// r*8 + (kc ^ (r&7)) -> fragment ds_read_b128 spreads bank groups.
__global__ __launch_bounds__(256, 1) void gemm_fuzzy(const unsigned short* __restrict__ A,
                                                     const unsigned short* __restrict__ Bt,
                                                     float* __restrict__ C) {
    __shared__ unsigned short As[2][BM * BK];  // 2 x 16 KB
    __shared__ unsigned short Bs[2][BN * BK];  // 2 x 16 KB

    const int tid  = threadIdx.x;
    const int lane = tid & 63;
    const int wave = tid >> 6;
    const int quad = lane >> 4;
    const int l16  = lane & 15;
    const int wm   = (wave >> 1) * 64;   // waves tile 2x2 over 128x128
    const int wn   = (wave & 1) * 64;
    const int bm   = (blockIdx.x >> 3) * BM;   // 32 m-blocks
    const int bn   = (blockIdx.x & 7) * BN;    // 8 n-blocks -> XCD-clustered

    // staging: 1024 chunks (16B) per operand tile, 4 per thread each
    int arow[4], adst[4];
    const unsigned short* Ag[4];
    const unsigned short* Bg[4];
#pragma unroll
    for (int r = 0; r < 4; ++r) {
        int c = tid + r * 256;
        int row = c >> 3, kc = c & 7;
        arow[r] = row;
        adst[r] = (row * 8 + (kc ^ (row & 7))) * 8;       // swizzled ushort idx
        Ag[r] = A  + (size_t)(bm + row) * IN + kc * 8;
        Bg[r] = Bt + (size_t)(bn + row) * IN + kc * 8;
    }

    bf16x8 rA[2][4], rB[2][4];

    // prologue: tile0 -> regs -> LDS0; tile1 -> regs
#pragma unroll
    for (int r = 0; r < 4; ++r) { rA[0][r] = *(const bf16x8*)Ag[r]; rB[0][r] = *(const bf16x8*)Bg[r]; }
#pragma unroll
    for (int r = 0; r < 4; ++r) {
        *(bf16x8*)&As[0][adst[r]] = rA[0][r];
        *(bf16x8*)&Bs[0][adst[r]] = rB[0][r];
    }
#pragma unroll
    for (int r = 0; r < 4; ++r) { rA[1][r] = *(const bf16x8*)(Ag[r] + BK); rB[1][r] = *(const bf16x8*)(Bg[r] + BK); }
    __syncthreads();

    f32x4 acc[4][4] = {};
    const int NIT = IN / BK;  // 16

#pragma unroll
    for (int i = 0; i < NIT; ++i) {
        // loads for tile i+2 into the reg set freed when tile i was written (iter i-1)
        if (i + 2 < NIT) {
            int k0 = (i + 2) * BK;
#pragma unroll
            for (int r = 0; r < 4; ++r) {
                rA[i & 1][r] = *(const bf16x8*)(Ag[r] + k0);
                rB[i & 1][r] = *(const bf16x8*)(Bg[r] + k0);
            }
        }

        const unsigned short* as = As[i & 1];
        const unsigned short* bs = Bs[i & 1];
#pragma unroll
        for (int s = 0; s < 2; ++s) {
            const int kc = s * 4 + quad;
            bf16x8 af[4], bfr[4];
#pragma unroll
            for (int mt = 0; mt < 4; ++mt) {
                int row = wm + mt * 16 + l16;
                af[mt] = *(const bf16x8*)&as[(row * 8 + (kc ^ (row & 7))) * 8];
            }
#pragma unroll
            for (int nt = 0; nt < 4; ++nt) {
                int row = wn + nt * 16 + l16;
                bfr[nt] = *(const bf16x8*)&bs[(row * 8 + (kc ^ (row & 7))) * 8];
            }
#pragma unroll
            for (int mt = 0; mt < 4; ++mt)
#pragma unroll
                for (int nt = 0; nt < 4; ++nt)
                    acc[mt][nt] = __builtin_amdgcn_mfma_f32_16x16x32_bf16(
                        af[mt], bfr[nt], acc[mt][nt], 0, 0, 0);
        }

        // stage tile i+1 (loaded a full iteration ago) -> LDS
        if (i + 1 < NIT) {
            int nb = (i + 1) & 1;
#pragma unroll
            for (int r = 0; r < 4; ++r) {
                *(bf16x8*)&As[nb][adst[r]] = rA[nb][r];
                *(bf16x8*)&Bs[nb][adst[r]] = rB[nb][r];
            }
        }
        __syncthreads();  // lgkm drain only — global loads stay in flight
    }

    // epilogue: C/D layout col=lane&15, row=quad*4+reg; fuse 1-s and clamp
#pragma unroll
    for (int mt = 0; mt < 4; ++mt) {
#pragma unroll
        for (int nt = 0; nt < 4; ++nt) {
#pragma unroll
            for (int r = 0; r < 4; ++r) {
                int row = bm + wm + mt * 16 + quad * 4 + r;
                int col = bn + wn + nt * 16 + l16;
                float v = 1.0f - acc[mt][nt][r];
                C[(size_t)row * OUT + col] = fmaxf(v, 0.0f);
            }
        }
    }
}

extern "C" void kernel_launch(void* const* d_in, const int* in_sizes, int n_in,
                              void* d_out, int out_size, void* d_ws, size_t ws_size,
                              hipStream_t stream) {
    const float* xs = (const float*)d_in[0];       // [4096][1024]
    const float* wt = (const float*)d_in[1];       // [1024][1024]
    float* out = (float*)d_out;                    // [4096][1024]

    unsigned short* A  = (unsigned short*)d_ws;                       // 8 MB
    unsigned short* WT = (unsigned short*)((char*)d_ws + (size_t)Bsz * IN * 2);  // 2 MB

    prep_fused<<<2048 + 1024, 256, 0, stream>>>(xs, wt, A, WT);
    gemm_fuzzy<<<256, 256, 0, stream>>>(A, WT, out);
}